// Round 1
// baseline (92.424 us; speedup 1.0000x reference)
//
#include <hip/hip_runtime.h>
#include <math.h>

// Loss_20495583936604: pairwise BCE-with-logits over same-segment, diff-label pairs.
//
// key = (b<<1)|y ; pair (i,j) valid  <=>  key_i ^ key_j == 1.
// bce(d=s_i-s_j, z=y_i) is symmetric under (i,j) swap, so we sum over ALL
// ordered pairs i!=j; sum and count both double, ratio unchanged.

#define TJ 512          // j-chunk per block (LDS-staged)
#define BLK 256         // threads per block; each thread owns one i

__global__ void __launch_bounds__(BLK) pair_loss_kernel(
    const int* __restrict__ b, const float* __restrict__ s,
    const int* __restrict__ y, double* __restrict__ ws_sum,
    unsigned int* __restrict__ ws_cnt, int n) {
  __shared__ float s_s[TJ];
  __shared__ int   s_k[TJ];

  const int i  = blockIdx.x * BLK + threadIdx.x;
  const int j0 = blockIdx.y * TJ;

  // Stage this block's j-chunk into LDS (coalesced).
  for (int t = threadIdx.x; t < TJ; t += BLK) {
    const int j = j0 + t;
    s_s[t] = s[j];
    s_k[t] = (b[j] << 1) | y[j];
  }
  __syncthreads();

  float acc = 0.0f;
  unsigned int cnt = 0;

  if (i < n) {
    const float si = s[i];
    const int   ki = (b[i] << 1) | y[i];
    const float zi = (float)(ki & 1);

    #pragma unroll 4
    for (int t = 0; t < TJ; ++t) {
      const int kj = s_k[t];            // broadcast read (all lanes same addr)
      if ((ki ^ kj) == 1) {             // same segment, differing label
        const float d  = si - s_s[t];
        const float ad = fabsf(d);
        // stable BCE-with-logits: max(d,0) - d*z + log1p(exp(-|d|))
        acc += fmaxf(d, 0.0f) - d * zi + log1pf(expf(-ad));
        cnt += 1u;
      }
    }
  }

  // Wave (64-lane) shuffle reduction.
  #pragma unroll
  for (int off = 32; off > 0; off >>= 1) {
    acc += __shfl_down(acc, off);
    cnt += __shfl_down(cnt, off);
  }

  // Cross-wave reduction in LDS.
  __shared__ float        wsum[BLK / 64];
  __shared__ unsigned int wcnt[BLK / 64];
  const int wave = threadIdx.x >> 6;
  const int lane = threadIdx.x & 63;
  if (lane == 0) { wsum[wave] = acc; wcnt[wave] = cnt; }
  __syncthreads();
  if (threadIdx.x == 0) {
    float        a = 0.0f;
    unsigned int c = 0;
    #pragma unroll
    for (int w = 0; w < BLK / 64; ++w) { a += wsum[w]; c += wcnt[w]; }
    if (c > 0 || a != 0.0f) {
      atomicAdd(ws_sum, (double)a);   // device-scope f64 atomic (gfx90a+)
    }
    atomicAdd(ws_cnt, c);
  }
}

__global__ void finalize_kernel(const double* __restrict__ ws_sum,
                                const unsigned int* __restrict__ ws_cnt,
                                float* __restrict__ out) {
  const double sum = *ws_sum;
  const unsigned int cnt = *ws_cnt;
  out[0] = (cnt > 0) ? (float)(sum / (double)cnt) : 0.0f;
}

extern "C" void kernel_launch(void* const* d_in, const int* in_sizes, int n_in,
                              void* d_out, int out_size, void* d_ws, size_t ws_size,
                              hipStream_t stream) {
  const int*   b = (const int*)d_in[0];
  const float* s = (const float*)d_in[1];
  const int*   y = (const int*)d_in[2];
  float*       out = (float*)d_out;
  const int n = in_sizes[0];  // 8192

  double*       ws_sum = (double*)d_ws;
  unsigned int* ws_cnt = (unsigned int*)((char*)d_ws + sizeof(double));

  // Zero accumulators every call (harness does not re-poison between replays).
  hipMemsetAsync(d_ws, 0, sizeof(double) + sizeof(unsigned int), stream);

  dim3 grid((n + BLK - 1) / BLK, (n + TJ - 1) / TJ);  // 32 x 16 = 512 blocks
  pair_loss_kernel<<<grid, BLK, 0, stream>>>(b, s, y, ws_sum, ws_cnt, n);
  finalize_kernel<<<1, 1, 0, stream>>>(ws_sum, ws_cnt, out);
}

// Round 2
// 16.669 us; speedup vs baseline: 5.5445x; 5.5445x over previous
//
#include <hip/hip_runtime.h>
#include <math.h>

// Loss_20495583936604 — pairwise BCE over same-segment, diff-label pairs.
//
// Identity: for every unordered valid pair {i,j} (b equal, y differs), the
// reference's BCE term equals softplus(s_q - s_p) where q is the y==0 element
// and p the y==1 element (bce(d,0)=softplus(d), bce(d,1)=softplus(-d)).
// So: loss = [sum_seg sum_{q in Y0, p in Y1} softplus(s0_q - s1_p)]
//            / [sum_seg n0*n1]
// Only ~131K evals instead of 67M brute-force pair checks.

#define NSEG 128
#define BLK  256
#define CAP  1024   // per-(segment,label) capacity; avg occupancy is 32

__global__ void __launch_bounds__(BLK) seg_pair_partial(
    const int* __restrict__ b, const float* __restrict__ s,
    const int* __restrict__ y, double* __restrict__ psum,
    int* __restrict__ pcnt, int n) {
  const int seg = blockIdx.x;
  __shared__ float s0[CAP];   // scores with y==0 in this segment
  __shared__ float s1[CAP];   // scores with y==1 in this segment
  __shared__ int   c0, c1;
  if (threadIdx.x == 0) { c0 = 0; c1 = 0; }
  __syncthreads();

  // ---- Phase 1: scan b (int4-vectorized), gather this segment's scores ----
  const int4* b4 = (const int4*)b;
  const int   n4 = n >> 2;
  for (int t = threadIdx.x; t < n4; t += BLK) {
    const int4 bb = b4[t];
    const int  i0 = t << 2;
    if (bb.x == seg) { const int l = y[i0+0]; const int pos = atomicAdd(l ? &c1 : &c0, 1); if (pos < CAP) (l ? s1 : s0)[pos] = s[i0+0]; }
    if (bb.y == seg) { const int l = y[i0+1]; const int pos = atomicAdd(l ? &c1 : &c0, 1); if (pos < CAP) (l ? s1 : s0)[pos] = s[i0+1]; }
    if (bb.z == seg) { const int l = y[i0+2]; const int pos = atomicAdd(l ? &c1 : &c0, 1); if (pos < CAP) (l ? s1 : s0)[pos] = s[i0+2]; }
    if (bb.w == seg) { const int l = y[i0+3]; const int pos = atomicAdd(l ? &c1 : &c0, 1); if (pos < CAP) (l ? s1 : s0)[pos] = s[i0+3]; }
  }
  // scalar tail (n % 4)
  for (int i = (n4 << 2) + threadIdx.x; i < n; i += BLK) {
    if (b[i] == seg) { const int l = y[i]; const int pos = atomicAdd(l ? &c1 : &c0, 1); if (pos < CAP) (l ? s1 : s0)[pos] = s[i]; }
  }
  __syncthreads();

  // ---- Phase 2: evaluate the n1 x n0 pair grid ----
  const int m0 = min(c0, CAP), m1 = min(c1, CAP);
  const int m  = m0 * m1;
  float acc = 0.0f;
  if (m0 > 0) {
    const float rcp = 1.0f / (float)m0;
    for (int w = threadIdx.x; w < m; w += BLK) {
      // w -> (p, q) without integer divide: float-reciprocal + correction
      int p = (int)((float)w * rcp);
      int q = w - p * m0;
      if (q < 0)        { --p; q += m0; }
      else if (q >= m0) { ++p; q -= m0; }
      const float x = s0[q] - s1[p];
      // softplus(x) = max(x,0) + log1p(exp(-|x|))
      acc += fmaxf(x, 0.0f) + log1pf(__expf(-fabsf(x)));
    }
  }

  // ---- Phase 3: block reduce, write partials ----
  #pragma unroll
  for (int off = 32; off > 0; off >>= 1) acc += __shfl_down(acc, off);
  __shared__ float wpart[BLK / 64];
  const int wv = threadIdx.x >> 6, ln = threadIdx.x & 63;
  if (ln == 0) wpart[wv] = acc;
  __syncthreads();
  if (threadIdx.x == 0) {
    double t = 0.0;
    #pragma unroll
    for (int k = 0; k < BLK / 64; ++k) t += (double)wpart[k];
    psum[seg] = t;          // written unconditionally every call -> no memset
    pcnt[seg] = m;
  }
}

__global__ void __launch_bounds__(NSEG) finalize_kernel(
    const double* __restrict__ psum, const int* __restrict__ pcnt,
    float* __restrict__ out) {
  double a = psum[threadIdx.x];
  int    c = pcnt[threadIdx.x];
  #pragma unroll
  for (int off = 32; off > 0; off >>= 1) {
    a += __shfl_down(a, off);
    c += __shfl_down(c, off);
  }
  __shared__ double sa[2];
  __shared__ int    sc[2];
  const int wv = threadIdx.x >> 6, ln = threadIdx.x & 63;
  if (ln == 0) { sa[wv] = a; sc[wv] = c; }
  __syncthreads();
  if (threadIdx.x == 0) {
    const double sum = sa[0] + sa[1];
    const int    cnt = sc[0] + sc[1];
    out[0] = (cnt > 0) ? (float)(sum / (double)cnt) : 0.0f;
  }
}

extern "C" void kernel_launch(void* const* d_in, const int* in_sizes, int n_in,
                              void* d_out, int out_size, void* d_ws, size_t ws_size,
                              hipStream_t stream) {
  const int*   b = (const int*)d_in[0];
  const float* s = (const float*)d_in[1];
  const int*   y = (const int*)d_in[2];
  float*       out = (float*)d_out;
  const int n = in_sizes[0];  // 8192

  double* psum = (double*)d_ws;                       // 128 doubles
  int*    pcnt = (int*)((char*)d_ws + NSEG * sizeof(double));  // 128 ints

  seg_pair_partial<<<NSEG, BLK, 0, stream>>>(b, s, y, psum, pcnt, n);
  finalize_kernel<<<1, NSEG, 0, stream>>>(psum, pcnt, out);
}